// Round 2
// baseline (397.619 us; speedup 1.0000x reference)
//
#include <hip/hip_runtime.h>

// GraphSAGE (2x SAGEConv mean + global_mean_pool + linear) collapsed algebraically:
// out = (((St@W1l + Sw@W1r + Wsum*b1) @ W2l + (Sw@W1l + Sx@W1r + N*b1) @ W2r)/N + b2) @ Wout + bout
// d_i = max(indeg_i,1), ws_j = sum_{e:src=j} 1/d[dst_e], u_j = ws_j/d_j,
// t_k = sum_{e:src=k} u[dst_e], Sx = sum_k x_k, Sw = sum_k ws_k x_k, St = sum_k t_k x_k.
//
// R1: edge scatters use per-XCD replica arrays + workgroup-scope atomics so the
// atomic executes in the XCD-local L2 (device-scope atomics were going to the
// memory-side coherence point: 32B HBM write per atomic, 49.9 MB WRITE_SIZE).

#define NN   100000
#define NE   1600000
#define FEAT 128
#define NCLS 40

__device__ __forceinline__ int xcd_slot() {
    int x;
    asm("s_getreg_b32 %0, hwreg(HW_REG_XCC_ID)" : "=s"(x));
    return x & 7;
}

// ---- edge pass 1: in-degree histogram ----
template<int R>
__global__ __launch_bounds__(256) void k_count(const int4* __restrict__ dst4, int* __restrict__ cnt_rep) {
    int i = blockIdx.x * 256 + threadIdx.x;
    if (i >= NE / 4) return;
    int* c = cnt_rep + (R > 1 ? xcd_slot() * NN : 0);
    int4 d = dst4[i];
    if constexpr (R > 1) {
        __hip_atomic_fetch_add(&c[d.x], 1, __ATOMIC_RELAXED, __HIP_MEMORY_SCOPE_WORKGROUP);
        __hip_atomic_fetch_add(&c[d.y], 1, __ATOMIC_RELAXED, __HIP_MEMORY_SCOPE_WORKGROUP);
        __hip_atomic_fetch_add(&c[d.z], 1, __ATOMIC_RELAXED, __HIP_MEMORY_SCOPE_WORKGROUP);
        __hip_atomic_fetch_add(&c[d.w], 1, __ATOMIC_RELAXED, __HIP_MEMORY_SCOPE_WORKGROUP);
    } else {
        atomicAdd(&c[d.x], 1); atomicAdd(&c[d.y], 1);
        atomicAdd(&c[d.z], 1); atomicAdd(&c[d.w], 1);
    }
}

// sum cnt replicas; precompute 1/max(cnt,1)
template<int R>
__global__ __launch_bounds__(256) void k_inv(const int* __restrict__ cnt_rep,
                                             int* __restrict__ cnt, float* __restrict__ invc) {
    int i = blockIdx.x * 256 + threadIdx.x;
    if (i >= NN) return;
    int c = 0;
    #pragma unroll
    for (int r = 0; r < R; ++r) c += cnt_rep[(size_t)r * NN + i];
    cnt[i] = c;
    invc[i] = 1.0f / (float)(c > 0 ? c : 1);
}

// ---- edge pass 2: ws_j = sum_{e:src=j} invc[dst_e] ----
template<int R>
__global__ __launch_bounds__(256) void k_ws(const int4* __restrict__ src4, const int4* __restrict__ dst4,
                                            const float* __restrict__ invc, float* __restrict__ ws_rep) {
    int i = blockIdx.x * 256 + threadIdx.x;
    if (i >= NE / 4) return;
    float* w = ws_rep + (R > 1 ? xcd_slot() * NN : 0);
    int4 s = src4[i];
    int4 d = dst4[i];
    float a = invc[d.x], b = invc[d.y], c = invc[d.z], e = invc[d.w];
    if constexpr (R > 1) {
        __hip_atomic_fetch_add(&w[s.x], a, __ATOMIC_RELAXED, __HIP_MEMORY_SCOPE_WORKGROUP);
        __hip_atomic_fetch_add(&w[s.y], b, __ATOMIC_RELAXED, __HIP_MEMORY_SCOPE_WORKGROUP);
        __hip_atomic_fetch_add(&w[s.z], c, __ATOMIC_RELAXED, __HIP_MEMORY_SCOPE_WORKGROUP);
        __hip_atomic_fetch_add(&w[s.w], e, __ATOMIC_RELAXED, __HIP_MEMORY_SCOPE_WORKGROUP);
    } else {
        atomicAdd(&w[s.x], a); atomicAdd(&w[s.y], b);
        atomicAdd(&w[s.z], c); atomicAdd(&w[s.w], e);
    }
}

// sum ws replicas; u = ws / max(cnt,1)
template<int R>
__global__ __launch_bounds__(256) void k_u(const float* __restrict__ ws_rep, const int* __restrict__ cnt,
                                           float* __restrict__ ws, float* __restrict__ u) {
    int i = blockIdx.x * 256 + threadIdx.x;
    if (i >= NN) return;
    float w = 0.f;
    #pragma unroll
    for (int r = 0; r < R; ++r) w += ws_rep[(size_t)r * NN + i];
    ws[i] = w;
    int c = cnt[i];
    u[i] = w / (float)(c > 0 ? c : 1);
}

// ---- edge pass 3: t_k = sum_{e:src=k} u[dst_e] ----
template<int R>
__global__ __launch_bounds__(256) void k_t(const int4* __restrict__ src4, const int4* __restrict__ dst4,
                                           const float* __restrict__ u, float* __restrict__ t_rep) {
    int i = blockIdx.x * 256 + threadIdx.x;
    if (i >= NE / 4) return;
    float* t = t_rep + (R > 1 ? xcd_slot() * NN : 0);
    int4 s = src4[i];
    int4 d = dst4[i];
    float a = u[d.x], b = u[d.y], c = u[d.z], e = u[d.w];
    if constexpr (R > 1) {
        __hip_atomic_fetch_add(&t[s.x], a, __ATOMIC_RELAXED, __HIP_MEMORY_SCOPE_WORKGROUP);
        __hip_atomic_fetch_add(&t[s.y], b, __ATOMIC_RELAXED, __HIP_MEMORY_SCOPE_WORKGROUP);
        __hip_atomic_fetch_add(&t[s.z], c, __ATOMIC_RELAXED, __HIP_MEMORY_SCOPE_WORKGROUP);
        __hip_atomic_fetch_add(&t[s.w], e, __ATOMIC_RELAXED, __HIP_MEMORY_SCOPE_WORKGROUP);
    } else {
        atomicAdd(&t[s.x], a); atomicAdd(&t[s.y], b);
        atomicAdd(&t[s.z], c); atomicAdd(&t[s.w], e);
    }
}

template<int R>
__global__ __launch_bounds__(256) void k_tsum(const float* __restrict__ t_rep, float* __restrict__ t) {
    int i = blockIdx.x * 256 + threadIdx.x;
    if (i >= NN) return;
    float v = 0.f;
    #pragma unroll
    for (int r = 0; r < R; ++r) v += t_rep[(size_t)r * NN + i];
    t[i] = v;
}

// Three weighted feature sums over x [NN,128] in one pass.
__global__ __launch_bounds__(256) void k_featsums(const float* __restrict__ x,
                                                  const float* __restrict__ ws,
                                                  const float* __restrict__ t,
                                                  float* __restrict__ sums) {
    int lane = threadIdx.x & 31;
    int grp  = threadIdx.x >> 5;          // 0..7
    int row0 = blockIdx.x * 8 + grp;
    int rstride = gridDim.x * 8;

    float sx0=0,sx1=0,sx2=0,sx3=0;
    float sw0=0,sw1=0,sw2=0,sw3=0;
    float st0=0,st1=0,st2=0,st3=0;
    float wsum = 0.f;

    for (int r = row0; r < NN; r += rstride) {
        const float4* xr = (const float4*)(x + (size_t)r * FEAT);
        float4 v = xr[lane];
        float wr = ws[r];
        float tr = t[r];
        sx0 += v.x; sx1 += v.y; sx2 += v.z; sx3 += v.w;
        sw0 += wr*v.x; sw1 += wr*v.y; sw2 += wr*v.z; sw3 += wr*v.w;
        st0 += tr*v.x; st1 += tr*v.y; st2 += tr*v.z; st3 += tr*v.w;
        if (lane == 0) wsum += wr;
    }

    __shared__ float shx[8][32][4];
    __shared__ float shw[8][32][4];
    __shared__ float sht[8][32][4];
    __shared__ float shwsum[8];
    shx[grp][lane][0]=sx0; shx[grp][lane][1]=sx1; shx[grp][lane][2]=sx2; shx[grp][lane][3]=sx3;
    shw[grp][lane][0]=sw0; shw[grp][lane][1]=sw1; shw[grp][lane][2]=sw2; shw[grp][lane][3]=sw3;
    sht[grp][lane][0]=st0; sht[grp][lane][1]=st1; sht[grp][lane][2]=st2; sht[grp][lane][3]=st3;
    if (lane == 0) shwsum[grp] = wsum;
    __syncthreads();

    if (grp == 0) {
        float ax[4], aw[4], at[4];
        #pragma unroll
        for (int c = 0; c < 4; ++c) { ax[c]=shx[0][lane][c]; aw[c]=shw[0][lane][c]; at[c]=sht[0][lane][c]; }
        #pragma unroll
        for (int g = 1; g < 8; ++g) {
            #pragma unroll
            for (int c = 0; c < 4; ++c) {
                ax[c]+=shx[g][lane][c]; aw[c]+=shw[g][lane][c]; at[c]+=sht[g][lane][c];
            }
        }
        #pragma unroll
        for (int c = 0; c < 4; ++c) {
            atomicAdd(&sums[        4*lane + c], ax[c]);
            atomicAdd(&sums[FEAT  + 4*lane + c], aw[c]);
            atomicAdd(&sums[2*FEAT+ 4*lane + c], at[c]);
        }
        if (lane == 0) {
            float w = shwsum[0];
            #pragma unroll
            for (int g = 1; g < 8; ++g) w += shwsum[g];
            atomicAdd(&sums[3*FEAT], w);
        }
    }
}

// Single-block epilogue.
__global__ __launch_bounds__(128) void k_final(const float* __restrict__ sums,
                                               const float* __restrict__ W1l, const float* __restrict__ W1r,
                                               const float* __restrict__ b1,
                                               const float* __restrict__ W2l, const float* __restrict__ W2r,
                                               const float* __restrict__ b2,
                                               const float* __restrict__ Wout, const float* __restrict__ bout,
                                               float* __restrict__ out) {
    __shared__ float Sx[FEAT], Sw[FEAT], St[FEAT], M1[FEAT], S2[FEAT], G[FEAT];
    __shared__ float Wsum;
    int f = threadIdx.x;
    Sx[f] = sums[f];
    Sw[f] = sums[FEAT + f];
    St[f] = sums[2*FEAT + f];
    if (f == 0) Wsum = sums[3*FEAT];
    __syncthreads();

    float m1 = (float)NN * b1[f];
    float s2 = Wsum * b1[f];
    for (int k = 0; k < FEAT; ++k) {
        float wl = W1l[k*FEAT + f];
        float wr = W1r[k*FEAT + f];
        m1 += Sw[k]*wl + Sx[k]*wr;
        s2 += St[k]*wl + Sw[k]*wr;
    }
    M1[f] = m1; S2[f] = s2;
    __syncthreads();

    float g = 0.f;
    for (int k = 0; k < FEAT; ++k)
        g += S2[k]*W2l[k*FEAT + f] + M1[k]*W2r[k*FEAT + f];
    g = g * (1.0f/(float)NN) + b2[f];
    G[f] = g;
    __syncthreads();

    if (f < NCLS) {
        float o = bout[f];
        for (int k = 0; k < FEAT; ++k)
            o += G[k]*Wout[k*NCLS + f];
        out[f] = o;
    }
}

template<int R>
static void run_pipeline(const float* x, const int* src, const int* dst,
                         const float* W1l, const float* W1r, const float* b1,
                         const float* W2l, const float* W2r, const float* b2,
                         const float* Wout, const float* bout,
                         float* out, void* d_ws, hipStream_t stream) {
    // workspace layout (4-byte units)
    int*   cnt_rep = (int*)d_ws;                               // [R*NN]
    float* ws_rep  = (float*)d_ws + (size_t)R*NN;              // [R*NN]
    float* t_rep   = (float*)d_ws + (size_t)2*R*NN;            // [R*NN]
    float* sums    = (float*)d_ws + (size_t)3*R*NN;            // [512 pad]
    int*   cnt     = (int*)d_ws   + (size_t)3*R*NN + 512;      // [NN]
    float* invc    = (float*)d_ws + (size_t)3*R*NN + 512 + NN; // [NN]
    float* ws      = (float*)d_ws + (size_t)3*R*NN + 512 + 2*NN;
    float* u       = (float*)d_ws + (size_t)3*R*NN + 512 + 3*NN;
    float* t       = (float*)d_ws + (size_t)3*R*NN + 512 + 4*NN;

    // zero replicas + sums in one shot
    hipMemsetAsync(d_ws, 0, ((size_t)3*R*NN + 512) * 4, stream);

    const int4* src4 = (const int4*)src;
    const int4* dst4 = (const int4*)dst;
    const int EB4 = (NE/4 + 255) / 256;
    const int NB  = (NN + 255) / 256;

    k_count<R><<<EB4, 256, 0, stream>>>(dst4, cnt_rep);
    k_inv<R><<<NB, 256, 0, stream>>>(cnt_rep, cnt, invc);
    k_ws<R><<<EB4, 256, 0, stream>>>(src4, dst4, invc, ws_rep);
    k_u<R><<<NB, 256, 0, stream>>>(ws_rep, cnt, ws, u);
    k_t<R><<<EB4, 256, 0, stream>>>(src4, dst4, u, t_rep);
    k_tsum<R><<<NB, 256, 0, stream>>>(t_rep, t);
    k_featsums<<<256, 256, 0, stream>>>(x, ws, t, sums);
    k_final<<<1, 128, 0, stream>>>(sums, W1l, W1r, b1, W2l, W2r, b2, Wout, bout, out);
}

extern "C" void kernel_launch(void* const* d_in, const int* in_sizes, int n_in,
                              void* d_out, int out_size, void* d_ws, size_t ws_size,
                              hipStream_t stream) {
    const float* x    = (const float*)d_in[0];
    const int*   ei   = (const int*)d_in[1];     // [2, NE] flat: src then dst (int32 on device)
    const float* W1l  = (const float*)d_in[2];
    const float* W1r  = (const float*)d_in[3];
    const float* b1   = (const float*)d_in[4];
    const float* W2l  = (const float*)d_in[5];
    const float* W2r  = (const float*)d_in[6];
    const float* b2   = (const float*)d_in[7];
    const float* Wout = (const float*)d_in[8];
    const float* bout = (const float*)d_in[9];
    float* out = (float*)d_out;

    const int* src = ei;
    const int* dst = ei + NE;

    const size_t need8 = ((size_t)3*8*NN + 512 + 5*NN) * 4;  // ~11.6 MB
    if (ws_size >= need8) {
        run_pipeline<8>(x, src, dst, W1l, W1r, b1, W2l, W2r, b2, Wout, bout, out, d_ws, stream);
    } else {
        run_pipeline<1>(x, src, dst, W1l, W1r, b1, W2l, W2r, b2, Wout, bout, out, d_ws, stream);
    }
}

// Round 3
// 388.679 us; speedup vs baseline: 1.0230x; 1.0230x over previous
//
#include <hip/hip_runtime.h>

// GraphSAGE (2x SAGEConv mean + global_mean_pool + linear) collapsed algebraically:
// out = (((St@W1l + Sw@W1r + Wsum*b1) @ W2l + (Sw@W1l + Sx@W1r + N*b1) @ W2r)/N + b2) @ Wout + bout
// d_i = max(indeg_i,1), invc_i = 1/d_i, ws_j = sum_{e:src=j} invc[dst_e], u_j = ws_j*invc_j,
// t_k = sum_{e:src=k} u[dst_e]; Sx/Sw/St = x-weighted column sums; Wsum = sum ws.
//
// R2: per-XCD replica accumulators + workgroup-scope atomics (execute at the
// XCD-local TCC, not the memory-side coherence point). ONE shared replica
// buffer (3.2 MB) reused across all three edge passes; the merge kernels
// re-zero it. Total ws need: 5.2 MB. Distinct kernel names per path so the
// profile shows which ran.

#define NN   100000
#define NE   1600000
#define FEAT 128
#define NCLS 40
#define NXCD 8

__device__ __forceinline__ int xcd_slot() {
    int x;
    asm("s_getreg_b32 %0, hwreg(HW_REG_XCC_ID)" : "=s"(x));
    return x & 7;
}

#define WG_ADD_F(p, v) __hip_atomic_fetch_add((p), (v), __ATOMIC_RELAXED, __HIP_MEMORY_SCOPE_WORKGROUP)
#define WG_ADD_I(p, v) __hip_atomic_fetch_add((p), (v), __ATOMIC_RELAXED, __HIP_MEMORY_SCOPE_WORKGROUP)

// ======================= replica (XCD-local L2 atomic) path =======================

__global__ __launch_bounds__(256) void k_count_rep(const int4* __restrict__ dst4, int* __restrict__ rep) {
    int i = blockIdx.x * 256 + threadIdx.x;
    if (i >= NE / 4) return;
    int* c = rep + xcd_slot() * NN;
    int4 d = dst4[i];
    WG_ADD_I(&c[d.x], 1); WG_ADD_I(&c[d.y], 1);
    WG_ADD_I(&c[d.z], 1); WG_ADD_I(&c[d.w], 1);
}

// merge cnt replicas -> cnt, invc; zero replica buffer for next pass
__global__ __launch_bounds__(256) void k_inv_rep(int* __restrict__ rep,
                                                 int* __restrict__ cnt, float* __restrict__ invc) {
    int i = blockIdx.x * 256 + threadIdx.x;
    if (i >= NN) return;
    int c = 0;
    #pragma unroll
    for (int r = 0; r < NXCD; ++r) c += rep[(size_t)r * NN + i];
    #pragma unroll
    for (int r = 0; r < NXCD; ++r) rep[(size_t)r * NN + i] = 0;
    cnt[i] = c;
    invc[i] = 1.0f / (float)(c > 0 ? c : 1);
}

__global__ __launch_bounds__(256) void k_ws_rep(const int4* __restrict__ src4, const int4* __restrict__ dst4,
                                                const float* __restrict__ invc, float* __restrict__ rep) {
    int i = blockIdx.x * 256 + threadIdx.x;
    if (i >= NE / 4) return;
    float* w = rep + xcd_slot() * NN;
    int4 s = src4[i];
    int4 d = dst4[i];
    float a = invc[d.x], b = invc[d.y], c = invc[d.z], e = invc[d.w];
    WG_ADD_F(&w[s.x], a); WG_ADD_F(&w[s.y], b);
    WG_ADD_F(&w[s.z], c); WG_ADD_F(&w[s.w], e);
}

// merge ws replicas -> ws, u = ws*invc; zero replica buffer for next pass
__global__ __launch_bounds__(256) void k_u_rep(float* __restrict__ rep, const float* __restrict__ invc,
                                               float* __restrict__ ws, float* __restrict__ u) {
    int i = blockIdx.x * 256 + threadIdx.x;
    if (i >= NN) return;
    float w = 0.f;
    #pragma unroll
    for (int r = 0; r < NXCD; ++r) w += rep[(size_t)r * NN + i];
    #pragma unroll
    for (int r = 0; r < NXCD; ++r) rep[(size_t)r * NN + i] = 0.f;
    ws[i] = w;
    u[i] = w * invc[i];
}

__global__ __launch_bounds__(256) void k_t_rep(const int4* __restrict__ src4, const int4* __restrict__ dst4,
                                               const float* __restrict__ u, float* __restrict__ rep) {
    int i = blockIdx.x * 256 + threadIdx.x;
    if (i >= NE / 4) return;
    float* t = rep + xcd_slot() * NN;
    int4 s = src4[i];
    int4 d = dst4[i];
    float a = u[d.x], b = u[d.y], c = u[d.z], e = u[d.w];
    WG_ADD_F(&t[s.x], a); WG_ADD_F(&t[s.y], b);
    WG_ADD_F(&t[s.z], c); WG_ADD_F(&t[s.w], e);
}

__global__ __launch_bounds__(256) void k_tsum_rep(const float* __restrict__ rep, float* __restrict__ t) {
    int i = blockIdx.x * 256 + threadIdx.x;
    if (i >= NN) return;
    float v = 0.f;
    #pragma unroll
    for (int r = 0; r < NXCD; ++r) v += rep[(size_t)r * NN + i];
    t[i] = v;
}

// ======================= device-scope fallback path =======================

__global__ __launch_bounds__(256) void k_count_dev(const int4* __restrict__ dst4, int* __restrict__ cnt) {
    int i = blockIdx.x * 256 + threadIdx.x;
    if (i >= NE / 4) return;
    int4 d = dst4[i];
    atomicAdd(&cnt[d.x], 1); atomicAdd(&cnt[d.y], 1);
    atomicAdd(&cnt[d.z], 1); atomicAdd(&cnt[d.w], 1);
}

__global__ __launch_bounds__(256) void k_inv_dev(const int* __restrict__ cnt, float* __restrict__ invc) {
    int i = blockIdx.x * 256 + threadIdx.x;
    if (i >= NN) return;
    int c = cnt[i];
    invc[i] = 1.0f / (float)(c > 0 ? c : 1);
}

__global__ __launch_bounds__(256) void k_ws_dev(const int4* __restrict__ src4, const int4* __restrict__ dst4,
                                                const float* __restrict__ invc, float* __restrict__ ws) {
    int i = blockIdx.x * 256 + threadIdx.x;
    if (i >= NE / 4) return;
    int4 s = src4[i];
    int4 d = dst4[i];
    atomicAdd(&ws[s.x], invc[d.x]); atomicAdd(&ws[s.y], invc[d.y]);
    atomicAdd(&ws[s.z], invc[d.z]); atomicAdd(&ws[s.w], invc[d.w]);
}

__global__ __launch_bounds__(256) void k_u_dev(const float* __restrict__ ws, const float* __restrict__ invc,
                                               float* __restrict__ u) {
    int i = blockIdx.x * 256 + threadIdx.x;
    if (i >= NN) return;
    u[i] = ws[i] * invc[i];
}

__global__ __launch_bounds__(256) void k_t_dev(const int4* __restrict__ src4, const int4* __restrict__ dst4,
                                               const float* __restrict__ u, float* __restrict__ t) {
    int i = blockIdx.x * 256 + threadIdx.x;
    if (i >= NE / 4) return;
    int4 s = src4[i];
    int4 d = dst4[i];
    atomicAdd(&t[s.x], u[d.x]); atomicAdd(&t[s.y], u[d.y]);
    atomicAdd(&t[s.z], u[d.z]); atomicAdd(&t[s.w], u[d.w]);
}

// ======================= shared tail =======================

__global__ __launch_bounds__(256) void k_featsums(const float* __restrict__ x,
                                                  const float* __restrict__ ws,
                                                  const float* __restrict__ t,
                                                  float* __restrict__ sums) {
    int lane = threadIdx.x & 31;
    int grp  = threadIdx.x >> 5;          // 0..7
    int row0 = blockIdx.x * 8 + grp;
    int rstride = gridDim.x * 8;

    float sx0=0,sx1=0,sx2=0,sx3=0;
    float sw0=0,sw1=0,sw2=0,sw3=0;
    float st0=0,st1=0,st2=0,st3=0;
    float wsum = 0.f;

    for (int r = row0; r < NN; r += rstride) {
        const float4* xr = (const float4*)(x + (size_t)r * FEAT);
        float4 v = xr[lane];
        float wr = ws[r];
        float tr = t[r];
        sx0 += v.x; sx1 += v.y; sx2 += v.z; sx3 += v.w;
        sw0 += wr*v.x; sw1 += wr*v.y; sw2 += wr*v.z; sw3 += wr*v.w;
        st0 += tr*v.x; st1 += tr*v.y; st2 += tr*v.z; st3 += tr*v.w;
        if (lane == 0) wsum += wr;
    }

    __shared__ float shx[8][32][4];
    __shared__ float shw[8][32][4];
    __shared__ float sht[8][32][4];
    __shared__ float shwsum[8];
    shx[grp][lane][0]=sx0; shx[grp][lane][1]=sx1; shx[grp][lane][2]=sx2; shx[grp][lane][3]=sx3;
    shw[grp][lane][0]=sw0; shw[grp][lane][1]=sw1; shw[grp][lane][2]=sw2; shw[grp][lane][3]=sw3;
    sht[grp][lane][0]=st0; sht[grp][lane][1]=st1; sht[grp][lane][2]=st2; sht[grp][lane][3]=st3;
    if (lane == 0) shwsum[grp] = wsum;
    __syncthreads();

    if (grp == 0) {
        float ax[4], aw[4], at[4];
        #pragma unroll
        for (int c = 0; c < 4; ++c) { ax[c]=shx[0][lane][c]; aw[c]=shw[0][lane][c]; at[c]=sht[0][lane][c]; }
        #pragma unroll
        for (int g = 1; g < 8; ++g) {
            #pragma unroll
            for (int c = 0; c < 4; ++c) {
                ax[c]+=shx[g][lane][c]; aw[c]+=shw[g][lane][c]; at[c]+=sht[g][lane][c];
            }
        }
        #pragma unroll
        for (int c = 0; c < 4; ++c) {
            atomicAdd(&sums[        4*lane + c], ax[c]);
            atomicAdd(&sums[FEAT  + 4*lane + c], aw[c]);
            atomicAdd(&sums[2*FEAT+ 4*lane + c], at[c]);
        }
        if (lane == 0) {
            float w = shwsum[0];
            #pragma unroll
            for (int g = 1; g < 8; ++g) w += shwsum[g];
            atomicAdd(&sums[3*FEAT], w);
        }
    }
}

__global__ __launch_bounds__(128) void k_final(const float* __restrict__ sums,
                                               const float* __restrict__ W1l, const float* __restrict__ W1r,
                                               const float* __restrict__ b1,
                                               const float* __restrict__ W2l, const float* __restrict__ W2r,
                                               const float* __restrict__ b2,
                                               const float* __restrict__ Wout, const float* __restrict__ bout,
                                               float* __restrict__ out) {
    __shared__ float Sx[FEAT], Sw[FEAT], St[FEAT], M1[FEAT], S2[FEAT], G[FEAT];
    __shared__ float Wsum;
    int f = threadIdx.x;
    Sx[f] = sums[f];
    Sw[f] = sums[FEAT + f];
    St[f] = sums[2*FEAT + f];
    if (f == 0) Wsum = sums[3*FEAT];
    __syncthreads();

    float m1 = (float)NN * b1[f];
    float s2 = Wsum * b1[f];
    for (int k = 0; k < FEAT; ++k) {
        float wl = W1l[k*FEAT + f];
        float wr = W1r[k*FEAT + f];
        m1 += Sw[k]*wl + Sx[k]*wr;
        s2 += St[k]*wl + Sw[k]*wr;
    }
    M1[f] = m1; S2[f] = s2;
    __syncthreads();

    float g = 0.f;
    for (int k = 0; k < FEAT; ++k)
        g += S2[k]*W2l[k*FEAT + f] + M1[k]*W2r[k*FEAT + f];
    g = g * (1.0f/(float)NN) + b2[f];
    G[f] = g;
    __syncthreads();

    if (f < NCLS) {
        float o = bout[f];
        for (int k = 0; k < FEAT; ++k)
            o += G[k]*Wout[k*NCLS + f];
        out[f] = o;
    }
}

extern "C" void kernel_launch(void* const* d_in, const int* in_sizes, int n_in,
                              void* d_out, int out_size, void* d_ws, size_t ws_size,
                              hipStream_t stream) {
    const float* x    = (const float*)d_in[0];
    const int*   ei   = (const int*)d_in[1];     // [2, NE] flat: src then dst (int32 on device)
    const float* W1l  = (const float*)d_in[2];
    const float* W1r  = (const float*)d_in[3];
    const float* b1   = (const float*)d_in[4];
    const float* W2l  = (const float*)d_in[5];
    const float* W2r  = (const float*)d_in[6];
    const float* b2   = (const float*)d_in[7];
    const float* Wout = (const float*)d_in[8];
    const float* bout = (const float*)d_in[9];
    float* out = (float*)d_out;

    const int4* src4 = (const int4*)ei;
    const int4* dst4 = (const int4*)(ei + NE);

    const int EB4 = (NE/4 + 255) / 256;   // 1563
    const int NB  = (NN + 255) / 256;     // 391

    const size_t need_rep = ((size_t)NXCD*NN + 512 + 5*NN) * 4;   // ~5.2 MB

    if (ws_size >= need_rep) {
        // layout: rep[8*NN] | sums[512] | cnt[NN] | invc[NN] | ws[NN] | u[NN] | t[NN]
        int*   rep  = (int*)d_ws;
        float* repf = (float*)d_ws;
        float* sums = (float*)d_ws + (size_t)NXCD*NN;
        int*   cnt  = (int*)d_ws   + (size_t)NXCD*NN + 512;
        float* invc = (float*)d_ws + (size_t)NXCD*NN + 512 + NN;
        float* ws   = (float*)d_ws + (size_t)NXCD*NN + 512 + 2*NN;
        float* u    = (float*)d_ws + (size_t)NXCD*NN + 512 + 3*NN;
        float* t    = (float*)d_ws + (size_t)NXCD*NN + 512 + 4*NN;

        hipMemsetAsync(d_ws, 0, ((size_t)NXCD*NN + 512) * 4, stream);

        k_count_rep<<<EB4, 256, 0, stream>>>(dst4, rep);
        k_inv_rep<<<NB, 256, 0, stream>>>(rep, cnt, invc);
        k_ws_rep<<<EB4, 256, 0, stream>>>(src4, dst4, invc, repf);
        k_u_rep<<<NB, 256, 0, stream>>>(repf, invc, ws, u);
        k_t_rep<<<EB4, 256, 0, stream>>>(src4, dst4, u, repf);
        k_tsum_rep<<<NB, 256, 0, stream>>>(repf, t);
        k_featsums<<<256, 256, 0, stream>>>(x, ws, t, sums);
        k_final<<<1, 128, 0, stream>>>(sums, W1l, W1r, b1, W2l, W2r, b2, Wout, bout, out);
    } else {
        // layout: cnt[NN] | ws[NN] | t[NN] | sums[512] | invc[NN] | u[NN]
        int*   cnt  = (int*)d_ws;
        float* ws   = (float*)d_ws + NN;
        float* t    = (float*)d_ws + 2*NN;
        float* sums = (float*)d_ws + 3*NN;
        float* invc = (float*)d_ws + 3*NN + 512;
        float* u    = (float*)d_ws + 3*NN + 512 + NN;

        hipMemsetAsync(d_ws, 0, ((size_t)3*NN + 512) * 4, stream);

        k_count_dev<<<EB4, 256, 0, stream>>>(dst4, cnt);
        k_inv_dev<<<NB, 256, 0, stream>>>(cnt, invc);
        k_ws_dev<<<EB4, 256, 0, stream>>>(src4, dst4, invc, ws);
        k_u_dev<<<NB, 256, 0, stream>>>(ws, invc, u);
        k_t_dev<<<EB4, 256, 0, stream>>>(src4, dst4, u, t);
        k_featsums<<<256, 256, 0, stream>>>(x, ws, t, sums);
        k_final<<<1, 128, 0, stream>>>(sums, W1l, W1r, b1, W2l, W2r, b2, Wout, bout, out);
    }
}

// Round 4
// 227.441 us; speedup vs baseline: 1.7482x; 1.7089x over previous
//
#include <hip/hip_runtime.h>

// GraphSAGE (2x SAGEConv mean + global_mean_pool + linear) collapsed algebraically:
// out = (((St@W1l + Sw@W1r + Wsum*b1) @ W2l + (Sw@W1l + Sx@W1r + N*b1) @ W2r)/N + b2) @ Wout + bout
// invc_i = 1/max(indeg_i,1), ws_j = sum_{e:src=j} invc[dst_e], u_j = ws_j*invc_j,
// t_k = sum_{e:src=k} u[dst_e]; Sx/Sw/St = weighted column sums of x; Wsum = sum ws.
//
// R3: global atomics proved memory-side regardless of scope (R2: WRITE_SIZE
// unchanged at 49.9 MB with workgroup-scope replicas). This version does the
// three edge scatters with LDS range privatization: 8 node-ranges x 12500
// entries (50 KB LDS), grid (C chunks x 8 ranges), ds_add_f32 only, dense
// partial flush + dense merge. Zero global atomics on the edge passes.

#define NN    100000
#define NE    1600000
#define FEAT  128
#define NCLS  40
#define NR    8
#define RSIZE 12500   // NN / NR

// ======================= LDS-privatized edge passes =======================

template<int C>
__global__ __launch_bounds__(1024) void k_cnt_lds(const int4* __restrict__ dst4, int* __restrict__ partial) {
    __shared__ int tab[RSIZE];
    const int c = blockIdx.x, r = blockIdx.y;
    for (int j = threadIdx.x; j < RSIZE; j += 1024) tab[j] = 0;
    __syncthreads();
    const int base = r * RSIZE;
    const int per = (NE / 4) / C;
    const int i0 = c * per;
    for (int i = i0 + (int)threadIdx.x; i < i0 + per; i += 1024) {
        int4 d = dst4[i];
        unsigned a;
        a = (unsigned)(d.x - base); if (a < RSIZE) atomicAdd(&tab[a], 1);
        a = (unsigned)(d.y - base); if (a < RSIZE) atomicAdd(&tab[a], 1);
        a = (unsigned)(d.z - base); if (a < RSIZE) atomicAdd(&tab[a], 1);
        a = (unsigned)(d.w - base); if (a < RSIZE) atomicAdd(&tab[a], 1);
    }
    __syncthreads();
    int* out = partial + (size_t)(r * C + c) * RSIZE;
    for (int j = threadIdx.x; j < RSIZE; j += 1024) out[j] = tab[j];
}

// scatter val[dst] into table keyed by src; used for both the ws pass (val=invc)
// and the t pass (val=u)
template<int C>
__global__ __launch_bounds__(1024) void k_scat_lds(const int4* __restrict__ src4, const int4* __restrict__ dst4,
                                                   const float* __restrict__ val, float* __restrict__ partial) {
    __shared__ float tab[RSIZE];
    const int c = blockIdx.x, r = blockIdx.y;
    for (int j = threadIdx.x; j < RSIZE; j += 1024) tab[j] = 0.f;
    __syncthreads();
    const int base = r * RSIZE;
    const int per = (NE / 4) / C;
    const int i0 = c * per;
    for (int i = i0 + (int)threadIdx.x; i < i0 + per; i += 1024) {
        int4 s = src4[i];
        int4 d = dst4[i];
        unsigned a;
        a = (unsigned)(s.x - base); if (a < RSIZE) atomicAdd(&tab[a], val[d.x]);
        a = (unsigned)(s.y - base); if (a < RSIZE) atomicAdd(&tab[a], val[d.y]);
        a = (unsigned)(s.z - base); if (a < RSIZE) atomicAdd(&tab[a], val[d.z]);
        a = (unsigned)(s.w - base); if (a < RSIZE) atomicAdd(&tab[a], val[d.w]);
    }
    __syncthreads();
    float* out = partial + (size_t)(r * C + c) * RSIZE;
    for (int j = threadIdx.x; j < RSIZE; j += 1024) out[j] = tab[j];
}

template<int C>
__global__ __launch_bounds__(256) void k_merge_invc(const int* __restrict__ partial, float* __restrict__ invc) {
    int i = blockIdx.x * 256 + threadIdx.x;
    if (i >= NN) return;
    int r = i / RSIZE, j = i - r * RSIZE;
    const int* p = partial + (size_t)r * C * RSIZE + j;
    int cn = 0;
    #pragma unroll 8
    for (int c = 0; c < C; ++c) cn += p[(size_t)c * RSIZE];
    invc[i] = 1.0f / (float)(cn > 0 ? cn : 1);
}

template<int C>
__global__ __launch_bounds__(256) void k_merge_ws(const float* __restrict__ partial, const float* __restrict__ invc,
                                                  float* __restrict__ ws, float* __restrict__ u) {
    int i = blockIdx.x * 256 + threadIdx.x;
    if (i >= NN) return;
    int r = i / RSIZE, j = i - r * RSIZE;
    const float* p = partial + (size_t)r * C * RSIZE + j;
    float w = 0.f;
    #pragma unroll 8
    for (int c = 0; c < C; ++c) w += p[(size_t)c * RSIZE];
    ws[i] = w;
    u[i] = w * invc[i];
}

template<int C>
__global__ __launch_bounds__(256) void k_merge_t(const float* __restrict__ partial, float* __restrict__ t) {
    int i = blockIdx.x * 256 + threadIdx.x;
    if (i >= NN) return;
    int r = i / RSIZE, j = i - r * RSIZE;
    const float* p = partial + (size_t)r * C * RSIZE + j;
    float v = 0.f;
    #pragma unroll 8
    for (int c = 0; c < C; ++c) v += p[(size_t)c * RSIZE];
    t[i] = v;
}

// ======================= device-scope fallback (tiny ws_size) =======================

__global__ __launch_bounds__(256) void k_count_dev(const int4* __restrict__ dst4, int* __restrict__ cnt) {
    int i = blockIdx.x * 256 + threadIdx.x;
    if (i >= NE / 4) return;
    int4 d = dst4[i];
    atomicAdd(&cnt[d.x], 1); atomicAdd(&cnt[d.y], 1);
    atomicAdd(&cnt[d.z], 1); atomicAdd(&cnt[d.w], 1);
}

__global__ __launch_bounds__(256) void k_inv_dev(const int* __restrict__ cnt, float* __restrict__ invc) {
    int i = blockIdx.x * 256 + threadIdx.x;
    if (i >= NN) return;
    int c = cnt[i];
    invc[i] = 1.0f / (float)(c > 0 ? c : 1);
}

__global__ __launch_bounds__(256) void k_ws_dev(const int4* __restrict__ src4, const int4* __restrict__ dst4,
                                                const float* __restrict__ invc, float* __restrict__ ws) {
    int i = blockIdx.x * 256 + threadIdx.x;
    if (i >= NE / 4) return;
    int4 s = src4[i];
    int4 d = dst4[i];
    atomicAdd(&ws[s.x], invc[d.x]); atomicAdd(&ws[s.y], invc[d.y]);
    atomicAdd(&ws[s.z], invc[d.z]); atomicAdd(&ws[s.w], invc[d.w]);
}

__global__ __launch_bounds__(256) void k_u_dev(const float* __restrict__ ws, const float* __restrict__ invc,
                                               float* __restrict__ u) {
    int i = blockIdx.x * 256 + threadIdx.x;
    if (i >= NN) return;
    u[i] = ws[i] * invc[i];
}

__global__ __launch_bounds__(256) void k_t_dev(const int4* __restrict__ src4, const int4* __restrict__ dst4,
                                               const float* __restrict__ u, float* __restrict__ t) {
    int i = blockIdx.x * 256 + threadIdx.x;
    if (i >= NE / 4) return;
    int4 s = src4[i];
    int4 d = dst4[i];
    atomicAdd(&t[s.x], u[d.x]); atomicAdd(&t[s.y], u[d.y]);
    atomicAdd(&t[s.z], u[d.z]); atomicAdd(&t[s.w], u[d.w]);
}

// ======================= shared tail =======================

__global__ __launch_bounds__(256) void k_featsums(const float* __restrict__ x,
                                                  const float* __restrict__ ws,
                                                  const float* __restrict__ t,
                                                  float* __restrict__ sums) {
    int lane = threadIdx.x & 31;
    int grp  = threadIdx.x >> 5;          // 0..7
    int row0 = blockIdx.x * 8 + grp;
    int rstride = gridDim.x * 8;

    float sx0=0,sx1=0,sx2=0,sx3=0;
    float sw0=0,sw1=0,sw2=0,sw3=0;
    float st0=0,st1=0,st2=0,st3=0;
    float wsum = 0.f;

    for (int r = row0; r < NN; r += rstride) {
        const float4* xr = (const float4*)(x + (size_t)r * FEAT);
        float4 v = xr[lane];
        float wr = ws[r];
        float tr = t[r];
        sx0 += v.x; sx1 += v.y; sx2 += v.z; sx3 += v.w;
        sw0 += wr*v.x; sw1 += wr*v.y; sw2 += wr*v.z; sw3 += wr*v.w;
        st0 += tr*v.x; st1 += tr*v.y; st2 += tr*v.z; st3 += tr*v.w;
        if (lane == 0) wsum += wr;
    }

    __shared__ float shx[8][32][4];
    __shared__ float shw[8][32][4];
    __shared__ float sht[8][32][4];
    __shared__ float shwsum[8];
    shx[grp][lane][0]=sx0; shx[grp][lane][1]=sx1; shx[grp][lane][2]=sx2; shx[grp][lane][3]=sx3;
    shw[grp][lane][0]=sw0; shw[grp][lane][1]=sw1; shw[grp][lane][2]=sw2; shw[grp][lane][3]=sw3;
    sht[grp][lane][0]=st0; sht[grp][lane][1]=st1; sht[grp][lane][2]=st2; sht[grp][lane][3]=st3;
    if (lane == 0) shwsum[grp] = wsum;
    __syncthreads();

    if (grp == 0) {
        float ax[4], aw[4], at[4];
        #pragma unroll
        for (int c = 0; c < 4; ++c) { ax[c]=shx[0][lane][c]; aw[c]=shw[0][lane][c]; at[c]=sht[0][lane][c]; }
        #pragma unroll
        for (int g = 1; g < 8; ++g) {
            #pragma unroll
            for (int c = 0; c < 4; ++c) {
                ax[c]+=shx[g][lane][c]; aw[c]+=shw[g][lane][c]; at[c]+=sht[g][lane][c];
            }
        }
        #pragma unroll
        for (int c = 0; c < 4; ++c) {
            atomicAdd(&sums[        4*lane + c], ax[c]);
            atomicAdd(&sums[FEAT  + 4*lane + c], aw[c]);
            atomicAdd(&sums[2*FEAT+ 4*lane + c], at[c]);
        }
        if (lane == 0) {
            float w = shwsum[0];
            #pragma unroll
            for (int g = 1; g < 8; ++g) w += shwsum[g];
            atomicAdd(&sums[3*FEAT], w);
        }
    }
}

__global__ __launch_bounds__(128) void k_final(const float* __restrict__ sums,
                                               const float* __restrict__ W1l, const float* __restrict__ W1r,
                                               const float* __restrict__ b1,
                                               const float* __restrict__ W2l, const float* __restrict__ W2r,
                                               const float* __restrict__ b2,
                                               const float* __restrict__ Wout, const float* __restrict__ bout,
                                               float* __restrict__ out) {
    __shared__ float Sx[FEAT], Sw[FEAT], St[FEAT], M1[FEAT], S2[FEAT], G[FEAT];
    __shared__ float Wsum;
    int f = threadIdx.x;
    Sx[f] = sums[f];
    Sw[f] = sums[FEAT + f];
    St[f] = sums[2*FEAT + f];
    if (f == 0) Wsum = sums[3*FEAT];
    __syncthreads();

    float m1 = (float)NN * b1[f];
    float s2 = Wsum * b1[f];
    for (int k = 0; k < FEAT; ++k) {
        float wl = W1l[k*FEAT + f];
        float wr = W1r[k*FEAT + f];
        m1 += Sw[k]*wl + Sx[k]*wr;
        s2 += St[k]*wl + Sw[k]*wr;
    }
    M1[f] = m1; S2[f] = s2;
    __syncthreads();

    float g = 0.f;
    for (int k = 0; k < FEAT; ++k)
        g += S2[k]*W2l[k*FEAT + f] + M1[k]*W2r[k*FEAT + f];
    g = g * (1.0f/(float)NN) + b2[f];
    G[f] = g;
    __syncthreads();

    if (f < NCLS) {
        float o = bout[f];
        for (int k = 0; k < FEAT; ++k)
            o += G[k]*Wout[k*NCLS + f];
        out[f] = o;
    }
}

// ======================= driver =======================

template<int C>
static void run_lds(const float* x, const int4* src4, const int4* dst4,
                    const float* W1l, const float* W1r, const float* b1,
                    const float* W2l, const float* W2r, const float* b2,
                    const float* Wout, const float* bout,
                    float* out, void* d_ws, hipStream_t stream) {
    // layout: partial[NR*C*RSIZE] | sums[640] | invc[NN] | ws[NN] | u[NN] | t[NN]
    float* partial = (float*)d_ws;
    size_t po = (size_t)NR * C * RSIZE;
    float* sums = (float*)d_ws + po;
    float* invc = (float*)d_ws + po + 640;
    float* ws   = (float*)d_ws + po + 640 + (size_t)NN;
    float* u    = (float*)d_ws + po + 640 + (size_t)2*NN;
    float* t    = (float*)d_ws + po + 640 + (size_t)3*NN;

    hipMemsetAsync(sums, 0, 640 * 4, stream);   // partial needs no init: fully written

    dim3 eg(C, NR);
    const int NB = (NN + 255) / 256;

    k_cnt_lds<C><<<eg, 1024, 0, stream>>>(dst4, (int*)partial);
    k_merge_invc<C><<<NB, 256, 0, stream>>>((const int*)partial, invc);
    k_scat_lds<C><<<eg, 1024, 0, stream>>>(src4, dst4, invc, partial);
    k_merge_ws<C><<<NB, 256, 0, stream>>>(partial, invc, ws, u);
    k_scat_lds<C><<<eg, 1024, 0, stream>>>(src4, dst4, u, partial);
    k_merge_t<C><<<NB, 256, 0, stream>>>(partial, t);
    k_featsums<<<256, 256, 0, stream>>>(x, ws, t, sums);
    k_final<<<1, 128, 0, stream>>>(sums, W1l, W1r, b1, W2l, W2r, b2, Wout, bout, out);
}

extern "C" void kernel_launch(void* const* d_in, const int* in_sizes, int n_in,
                              void* d_out, int out_size, void* d_ws, size_t ws_size,
                              hipStream_t stream) {
    const float* x    = (const float*)d_in[0];
    const int*   ei   = (const int*)d_in[1];     // [2, NE] flat: src then dst (int32 on device)
    const float* W1l  = (const float*)d_in[2];
    const float* W1r  = (const float*)d_in[3];
    const float* b1   = (const float*)d_in[4];
    const float* W2l  = (const float*)d_in[5];
    const float* W2r  = (const float*)d_in[6];
    const float* b2   = (const float*)d_in[7];
    const float* Wout = (const float*)d_in[8];
    const float* bout = (const float*)d_in[9];
    float* out = (float*)d_out;

    const int4* src4 = (const int4*)ei;
    const int4* dst4 = (const int4*)(ei + NE);

    auto need = [](int C) { return ((size_t)NR * C * RSIZE + 640 + (size_t)4 * NN) * 4; };

    if (ws_size >= need(64)) {
        run_lds<64>(x, src4, dst4, W1l, W1r, b1, W2l, W2r, b2, Wout, bout, out, d_ws, stream);
    } else if (ws_size >= need(32)) {
        run_lds<32>(x, src4, dst4, W1l, W1r, b1, W2l, W2r, b2, Wout, bout, out, d_ws, stream);
    } else if (ws_size >= need(16)) {
        run_lds<16>(x, src4, dst4, W1l, W1r, b1, W2l, W2r, b2, Wout, bout, out, d_ws, stream);
    } else {
        // device-scope atomic fallback (R0 behavior, ~2.1 MB ws)
        int*   cnt  = (int*)d_ws;
        float* wsv  = (float*)d_ws + NN;
        float* t    = (float*)d_ws + 2*NN;
        float* sums = (float*)d_ws + 3*NN;
        float* invc = (float*)d_ws + 3*NN + 640;
        float* u    = (float*)d_ws + 3*NN + 640 + NN;

        hipMemsetAsync(d_ws, 0, ((size_t)3*NN + 640) * 4, stream);

        const int EB4 = (NE/4 + 255) / 256;
        const int NB  = (NN + 255) / 256;
        k_count_dev<<<EB4, 256, 0, stream>>>(dst4, cnt);
        k_inv_dev<<<NB, 256, 0, stream>>>(cnt, invc);
        k_ws_dev<<<EB4, 256, 0, stream>>>(src4, dst4, invc, wsv);
        k_u_dev<<<NB, 256, 0, stream>>>(wsv, invc, u);
        k_t_dev<<<EB4, 256, 0, stream>>>(src4, dst4, u, t);
        k_featsums<<<256, 256, 0, stream>>>(x, wsv, t, sums);
        k_final<<<1, 128, 0, stream>>>(sums, W1l, W1r, b1, W2l, W2r, b2, Wout, bout, out);
    }
}